// Round 5
// baseline (228.943 us; speedup 1.0000x reference)
//
#include <hip/hip_runtime.h>
#include <hip/hip_bf16.h>
#include <stdint.h>

typedef __attribute__((ext_vector_type(8))) __bf16 bf16x8;
typedef __attribute__((ext_vector_type(4))) __bf16 bf16x4;
typedef __attribute__((ext_vector_type(4))) float f32x4;

#define AS1 __attribute__((address_space(1)))
#define AS3 __attribute__((address_space(3)))

__device__ __forceinline__ void load_lds16(const void* g, void* l) {
    __builtin_amdgcn_global_load_lds((const AS1 void*)g, (AS3 void*)l, 16, 0, 0);
}

__device__ __forceinline__ float m3(float a, float b, float c) {
    return fmaxf(fmaxf(a, b), c);  // clang fuses to v_max3_f32
}

constexpr float QSCALE = 0.18033688011112042f;  // 64^-0.5 * log2(e)

// sigma: storage position of kv (0..31) within a 32-column block of Vt,
// chosen so the PV B-operand slots match the P-register slots (phi mapping).
__device__ __forceinline__ int sigma32(int kv) {
    return (kv < 16) ? ((kv >> 2) * 8 + (kv & 3))
                     : (((kv - 16) >> 2) * 8 + 4 + ((kv - 16) & 3));
}

// ---------------------------------------------------------------------------
__global__ void cvt_x(const float4* __restrict__ x, bf16x4* __restrict__ o, int n4) {
    int i = blockIdx.x * blockDim.x + threadIdx.x;
    if (i >= n4) return;
    float4 v = x[i];
    bf16x4 r;
    r[0] = (__bf16)v.x; r[1] = (__bf16)v.y; r[2] = (__bf16)v.z; r[3] = (__bf16)v.w;
    o[i] = r;
}

// ---------------------------------------------------------------------------
__global__ void tconv(const float* __restrict__ src, __bf16* __restrict__ dst,
                      int R, int C) {
    __shared__ float tile[32][33];
    int c0 = blockIdx.x * 32, r0 = blockIdx.y * 32;
    int tx = threadIdx.x, ty = threadIdx.y;  // 32 x 8
    #pragma unroll
    for (int i = 0; i < 32; i += 8)
        tile[ty + i][tx] = src[(size_t)(r0 + ty + i) * C + c0 + tx];
    __syncthreads();
    #pragma unroll
    for (int i = 0; i < 32; i += 8)
        dst[(size_t)(c0 + ty + i) * R + r0 + tx] = (__bf16)tile[tx][ty + i];
}

// ---------------------------------------------------------------------------
// 128x128 bf16 GEMM, Bt is [N][K]. C = A @ Bt^T + bias.
// MODE 0: scatter Q (pre-scaled by QSCALE), K into [bh][n][d]; V transposed+
//         sigma-interleaved into Vt [bh][d][n'].  outp = q base.
// MODE 1: plain fp32 [M][Nn] output
template <int MODE>
__global__ __launch_bounds__(256)
void gemm128(const __bf16* __restrict__ A, const __bf16* __restrict__ Bt,
             const float* __restrict__ bias, void* __restrict__ outp,
             int M, int Nn, int K) {
    __shared__ __bf16 As[128][32];
    __shared__ __bf16 Bs[128][32];
    const int t = threadIdx.x;
    const int w = t >> 6, l = t & 63;
    const int lrow = l & 15, lhi = l >> 4;
    const int wr = (w >> 1) * 64, wc = (w & 1) * 64;
    const int m0 = blockIdx.y * 128, n0 = blockIdx.x * 128;

    f32x4 acc[4][4] = {};

    const int sr = t >> 2, sc = (t & 3) * 8;
    const __bf16* ag = A + (size_t)(m0 + sr) * K + sc;
    const __bf16* bg = Bt + (size_t)(n0 + sr) * K + sc;

    for (int kt = 0; kt < K; kt += 32) {
        load_lds16(ag, &As[sr][sc]);
        load_lds16(ag + (size_t)64 * K, &As[64 + sr][sc]);
        load_lds16(bg, &Bs[sr][sc]);
        load_lds16(bg + (size_t)64 * K, &Bs[64 + sr][sc]);
        ag += 32; bg += 32;
        __syncthreads();
        bf16x8 af[4], bfv[4];
        #pragma unroll
        for (int i = 0; i < 4; ++i)
            af[i] = *(const bf16x8*)(&As[wr + i * 16 + lrow][lhi * 8]);
        #pragma unroll
        for (int j = 0; j < 4; ++j)
            bfv[j] = *(const bf16x8*)(&Bs[wc + j * 16 + lrow][lhi * 8]);
        #pragma unroll
        for (int i = 0; i < 4; ++i)
            #pragma unroll
            for (int j = 0; j < 4; ++j)
                acc[i][j] = __builtin_amdgcn_mfma_f32_16x16x32_bf16(
                    af[i], bfv[j], acc[i][j], 0, 0, 0);
        __syncthreads();
    }

    #pragma unroll
    for (int i = 0; i < 4; ++i)
        #pragma unroll
        for (int j = 0; j < 4; ++j)
            #pragma unroll
            for (int r = 0; r < 4; ++r) {
                int row = m0 + wr + i * 16 + lhi * 4 + r;
                int col = n0 + wc + j * 16 + lrow;
                float val = acc[i][j][r] + bias[col];
                if (MODE == 0) {
                    int which = col >> 10;          // 0=q 1=k 2=v
                    int h = (col >> 6) & 15;
                    int d = col & 63;
                    int b = row >> 11;
                    int n = row & 2047;
                    int bh = (b << 4) + h;
                    if (which == 2) {
                        ((__bf16*)outp)[(size_t)2 * (32 * 2048 * 64) +
                                        ((size_t)bh * 64 + d) * 2048 +
                                        (n & ~31) + sigma32(n & 31)] = (__bf16)val;
                    } else {
                        if (which == 0) val *= QSCALE;
                        ((__bf16*)outp)[(size_t)which * (32 * 2048 * 64) +
                                        ((size_t)bh * 2048 + n) * 64 + d] = (__bf16)val;
                    }
                } else {
                    ((float*)outp)[(size_t)row * Nn + col] = val;
                }
            }
}

// ---------------------------------------------------------------------------
// Shared attention core macro bits are written out explicitly in both kernels.
// attn_fwd: single-pass fallback (normalizes in-kernel).
// attn_part: kv-split partial pass (blockIdx.z selects kv half), writes
//            unnormalized O (f32), m, l per q-row.
// q,k: [32][2048][64] (q pre-scaled)   vt: [32][64][2048] sigma-interleaved
// ---------------------------------------------------------------------------
__global__ __launch_bounds__(256)
void attn_fwd(const __bf16* __restrict__ q, const __bf16* __restrict__ k,
              const __bf16* __restrict__ vt, __bf16* __restrict__ out) {
    __shared__ __bf16 KsV[2][64][64];
    __shared__ __bf16 VsV[2][64][64];
    char* ksB = (char*)KsV;
    char* vsB = (char*)VsV;

    const int t = threadIdx.x;
    const int w = t >> 6, l = t & 63;
    const int lrow = l & 15, lhi = l >> 4;
    const int bh = blockIdx.y;
    const int q0 = blockIdx.x * 128 + w * 32;

    const __bf16* qp = q + ((size_t)bh * 2048 + q0) * 64;
    bf16x8 qfA0 = *(const bf16x8*)(qp + lrow * 64 + lhi * 8);
    bf16x8 qfA1 = *(const bf16x8*)(qp + lrow * 64 + 32 + lhi * 8);
    bf16x8 qfB0 = *(const bf16x8*)(qp + (16 + lrow) * 64 + lhi * 8);
    bf16x8 qfB1 = *(const bf16x8*)(qp + (16 + lrow) * 64 + 32 + lhi * 8);

    f32x4 oA[4] = {}, oB[4] = {};
    float mA = -1e30f, mB = -1e30f;
    float lA = 0.f, lB = 0.f;

    const __bf16* kg = k + (size_t)bh * 2048 * 64;
    const __bf16* vg = vt + (size_t)bh * 64 * 2048;

    const int sr = t >> 3;
    const int sw8 = ((t & 7) ^ (sr & 7)) * 8;
    const int rsw = (lrow & 7) << 4;

    {
        char* kd = ksB + t * 16;
        char* vd = vsB + t * 16;
        load_lds16(kg + (size_t)sr * 64 + sw8, kd);
        load_lds16(kg + (size_t)(32 + sr) * 64 + sw8, kd + 4096);
        load_lds16(vg + (size_t)sr * 2048 + sw8, vd);
        load_lds16(vg + (size_t)(32 + sr) * 2048 + sw8, vd + 4096);
    }

    const __bf16* kst  = kg + (size_t)(64 + sr) * 64 + sw8;
    const __bf16* kst2 = kst + 32 * 64;
    const __bf16* vst  = vg + (size_t)sr * 2048 + 64 + sw8;
    const __bf16* vst2 = vst + 32 * 2048;

    int cur = 0;
    for (int kv0 = 0; kv0 < 2048; kv0 += 64) {
        __syncthreads();
        if (kv0 + 64 < 2048) {
            char* kd = ksB + (cur ^ 1) * 8192 + t * 16;
            char* vd = vsB + (cur ^ 1) * 8192 + t * 16;
            load_lds16(kst, kd);
            load_lds16(kst2, kd + 4096);
            load_lds16(vst, vd);
            load_lds16(vst2, vd + 4096);
            kst += 4096; kst2 += 4096; vst += 64; vst2 += 64;
        }
        const char* kb = ksB + cur * 8192 + lrow * 128;
        const char* vb = vsB + cur * 8192 + lrow * 128;
        const int o0 = (lhi << 4) ^ rsw;
        const int o4 = ((4 + lhi) << 4) ^ rsw;

        f32x4 sA0 = {}, sA1 = {}, sA2 = {}, sA3 = {};
        f32x4 sB0 = {}, sB1 = {}, sB2 = {}, sB3 = {};
        __builtin_amdgcn_s_setprio(1);
        {
            bf16x8 kf0, kf1;
#define QK_GROUP(SA, SB, BASE)                                                 \
            kf0 = *(const bf16x8*)(kb + (BASE) + o0);                          \
            kf1 = *(const bf16x8*)(kb + (BASE) + o4);                          \
            SA = __builtin_amdgcn_mfma_f32_16x16x32_bf16(kf0, qfA0, SA, 0, 0, 0); \
            SA = __builtin_amdgcn_mfma_f32_16x16x32_bf16(kf1, qfA1, SA, 0, 0, 0); \
            SB = __builtin_amdgcn_mfma_f32_16x16x32_bf16(kf0, qfB0, SB, 0, 0, 0); \
            SB = __builtin_amdgcn_mfma_f32_16x16x32_bf16(kf1, qfB1, SB, 0, 0, 0);
            QK_GROUP(sA0, sB0, 0)
            QK_GROUP(sA1, sB1, 2048)
            QK_GROUP(sA2, sB2, 4096)
            QK_GROUP(sA3, sB3, 6144)
#undef QK_GROUP
        }
        __builtin_amdgcn_s_setprio(0);

        float u0 = m3(sA0[0], sA0[1], sA0[2]);
        float u1 = m3(sA0[3], sA1[0], sA1[1]);
        float u2 = m3(sA1[2], sA1[3], sA2[0]);
        float u3 = m3(sA2[1], sA2[2], sA2[3]);
        float u4 = m3(sA3[0], sA3[1], sA3[2]);
        float tmA = fmaxf(m3(u0, u1, u2), m3(u3, u4, sA3[3]));
        float v0 = m3(sB0[0], sB0[1], sB0[2]);
        float v1 = m3(sB0[3], sB1[0], sB1[1]);
        float v2 = m3(sB1[2], sB1[3], sB2[0]);
        float v3 = m3(sB2[1], sB2[2], sB2[3]);
        float v4 = m3(sB3[0], sB3[1], sB3[2]);
        float tmB = fmaxf(m3(v0, v1, v2), m3(v3, v4, sB3[3]));
        tmA = fmaxf(tmA, __shfl_xor(tmA, 16, 64));
        tmA = fmaxf(tmA, __shfl_xor(tmA, 32, 64));
        tmB = fmaxf(tmB, __shfl_xor(tmB, 16, 64));
        tmB = fmaxf(tmB, __shfl_xor(tmB, 32, 64));
        if (!__all(tmA <= mA + 8.0f && tmB <= mB + 8.0f)) {
            float mnA = fmaxf(mA, tmA), mnB = fmaxf(mB, tmB);
            float cA = __builtin_amdgcn_exp2f(mA - mnA);
            float cB = __builtin_amdgcn_exp2f(mB - mnB);
            lA *= cA; lB *= cB;
            #pragma unroll
            for (int dt = 0; dt < 4; ++dt)
                #pragma unroll
                for (int r = 0; r < 4; ++r) { oA[dt][r] *= cA; oB[dt][r] *= cB; }
            mA = mnA; mB = mnB;
        }
        float pA[16], pB[16];
        #pragma unroll
        for (int r = 0; r < 4; ++r) {
            pA[r]      = __builtin_amdgcn_exp2f(sA0[r] - mA);
            pA[4 + r]  = __builtin_amdgcn_exp2f(sA1[r] - mA);
            pA[8 + r]  = __builtin_amdgcn_exp2f(sA2[r] - mA);
            pA[12 + r] = __builtin_amdgcn_exp2f(sA3[r] - mA);
            pB[r]      = __builtin_amdgcn_exp2f(sB0[r] - mB);
            pB[4 + r]  = __builtin_amdgcn_exp2f(sB1[r] - mB);
            pB[8 + r]  = __builtin_amdgcn_exp2f(sB2[r] - mB);
            pB[12 + r] = __builtin_amdgcn_exp2f(sB3[r] - mB);
        }
        float rsA = 0.f, rsB = 0.f;
        #pragma unroll
        for (int j = 0; j < 16; ++j) { rsA += pA[j]; rsB += pB[j]; }
        lA += rsA; lB += rsB;

        bf16x8 pfA0, pfA1, pfB0, pfB1;
        #pragma unroll
        for (int j = 0; j < 8; ++j) {
            pfA0[j] = (__bf16)pA[j]; pfA1[j] = (__bf16)pA[8 + j];
            pfB0[j] = (__bf16)pB[j]; pfB1[j] = (__bf16)pB[8 + j];
        }

        __builtin_amdgcn_s_setprio(1);
        #pragma unroll
        for (int dt = 0; dt < 4; ++dt) {
            bf16x8 vf0 = *(const bf16x8*)(vb + dt * 2048 + o0);
            bf16x8 vf1 = *(const bf16x8*)(vb + dt * 2048 + o4);
            oA[dt] = __builtin_amdgcn_mfma_f32_16x16x32_bf16(vf0, pfA0, oA[dt], 0, 0, 0);
            oA[dt] = __builtin_amdgcn_mfma_f32_16x16x32_bf16(vf1, pfA1, oA[dt], 0, 0, 0);
            oB[dt] = __builtin_amdgcn_mfma_f32_16x16x32_bf16(vf0, pfB0, oB[dt], 0, 0, 0);
            oB[dt] = __builtin_amdgcn_mfma_f32_16x16x32_bf16(vf1, pfB1, oB[dt], 0, 0, 0);
        }
        __builtin_amdgcn_s_setprio(0);
        cur ^= 1;
    }

    lA += __shfl_xor(lA, 16, 64); lA += __shfl_xor(lA, 32, 64);
    lB += __shfl_xor(lB, 16, 64); lB += __shfl_xor(lB, 32, 64);
    float invA = __builtin_amdgcn_rcpf(lA);
    float invB = __builtin_amdgcn_rcpf(lB);

    const int b = bh >> 4, h = bh & 15;
    __bf16* orowA = out + ((size_t)(b * 2048 + q0 + lrow)) * 1024 + h * 64;
    __bf16* orowB = out + ((size_t)(b * 2048 + q0 + 16 + lrow)) * 1024 + h * 64;
    #pragma unroll
    for (int dt = 0; dt < 4; ++dt) {
        bf16x4 ovA, ovB;
        #pragma unroll
        for (int r = 0; r < 4; ++r) {
            ovA[r] = (__bf16)(oA[dt][r] * invA);
            ovB[r] = (__bf16)(oB[dt][r] * invB);
        }
        *(bf16x4*)(orowA + dt * 16 + lhi * 4) = ovA;
        *(bf16x4*)(orowB + dt * 16 + lhi * 4) = ovB;
    }
}

// ---------------------------------------------------------------------------
// kv-split partial pass: blockIdx.z = kv half. Writes unnormalized O (f32)
// into opart[z][bh][q][64] and (m, l) into ml[z][bh][q][2].
__global__ __launch_bounds__(256)
void attn_part(const __bf16* __restrict__ q, const __bf16* __restrict__ k,
               const __bf16* __restrict__ vt, float* __restrict__ opart,
               float* __restrict__ ml) {
    __shared__ __bf16 KsV[2][64][64];
    __shared__ __bf16 VsV[2][64][64];
    char* ksB = (char*)KsV;
    char* vsB = (char*)VsV;

    const int t = threadIdx.x;
    const int w = t >> 6, l = t & 63;
    const int lrow = l & 15, lhi = l >> 4;
    const int bh = blockIdx.y;
    const int z = blockIdx.z;
    const int kvb = z * 1024;
    const int q0 = blockIdx.x * 128 + w * 32;

    const __bf16* qp = q + ((size_t)bh * 2048 + q0) * 64;
    bf16x8 qfA0 = *(const bf16x8*)(qp + lrow * 64 + lhi * 8);
    bf16x8 qfA1 = *(const bf16x8*)(qp + lrow * 64 + 32 + lhi * 8);
    bf16x8 qfB0 = *(const bf16x8*)(qp + (16 + lrow) * 64 + lhi * 8);
    bf16x8 qfB1 = *(const bf16x8*)(qp + (16 + lrow) * 64 + 32 + lhi * 8);

    f32x4 oA[4] = {}, oB[4] = {};
    float mA = -1e30f, mB = -1e30f;
    float lA = 0.f, lB = 0.f;

    const __bf16* kg = k + (size_t)bh * 2048 * 64;
    const __bf16* vg = vt + (size_t)bh * 64 * 2048;

    const int sr = t >> 3;
    const int sw8 = ((t & 7) ^ (sr & 7)) * 8;
    const int rsw = (lrow & 7) << 4;

    {
        char* kd = ksB + t * 16;
        char* vd = vsB + t * 16;
        load_lds16(kg + (size_t)(kvb + sr) * 64 + sw8, kd);
        load_lds16(kg + (size_t)(kvb + 32 + sr) * 64 + sw8, kd + 4096);
        load_lds16(vg + (size_t)sr * 2048 + kvb + sw8, vd);
        load_lds16(vg + (size_t)(32 + sr) * 2048 + kvb + sw8, vd + 4096);
    }

    const __bf16* kst  = kg + (size_t)(kvb + 64 + sr) * 64 + sw8;
    const __bf16* kst2 = kst + 32 * 64;
    const __bf16* vst  = vg + (size_t)sr * 2048 + kvb + 64 + sw8;
    const __bf16* vst2 = vst + 32 * 2048;

    int cur = 0;
    for (int step = 0; step < 16; ++step) {
        __syncthreads();
        if (step < 15) {
            char* kd = ksB + (cur ^ 1) * 8192 + t * 16;
            char* vd = vsB + (cur ^ 1) * 8192 + t * 16;
            load_lds16(kst, kd);
            load_lds16(kst2, kd + 4096);
            load_lds16(vst, vd);
            load_lds16(vst2, vd + 4096);
            kst += 4096; kst2 += 4096; vst += 64; vst2 += 64;
        }
        const char* kb = ksB + cur * 8192 + lrow * 128;
        const char* vb = vsB + cur * 8192 + lrow * 128;
        const int o0 = (lhi << 4) ^ rsw;
        const int o4 = ((4 + lhi) << 4) ^ rsw;

        f32x4 sA0 = {}, sA1 = {}, sA2 = {}, sA3 = {};
        f32x4 sB0 = {}, sB1 = {}, sB2 = {}, sB3 = {};
        __builtin_amdgcn_s_setprio(1);
        {
            bf16x8 kf0, kf1;
#define QK_GROUP(SA, SB, BASE)                                                 \
            kf0 = *(const bf16x8*)(kb + (BASE) + o0);                          \
            kf1 = *(const bf16x8*)(kb + (BASE) + o4);                          \
            SA = __builtin_amdgcn_mfma_f32_16x16x32_bf16(kf0, qfA0, SA, 0, 0, 0); \
            SA = __builtin_amdgcn_mfma_f32_16x16x32_bf16(kf1, qfA1, SA, 0, 0, 0); \
            SB = __builtin_amdgcn_mfma_f32_16x16x32_bf16(kf0, qfB0, SB, 0, 0, 0); \
            SB = __builtin_amdgcn_mfma_f32_16x16x32_bf16(kf1, qfB1, SB, 0, 0, 0);
            QK_GROUP(sA0, sB0, 0)
            QK_GROUP(sA1, sB1, 2048)
            QK_GROUP(sA2, sB2, 4096)
            QK_GROUP(sA3, sB3, 6144)
#undef QK_GROUP
        }
        __builtin_amdgcn_s_setprio(0);

        float u0 = m3(sA0[0], sA0[1], sA0[2]);
        float u1 = m3(sA0[3], sA1[0], sA1[1]);
        float u2 = m3(sA1[2], sA1[3], sA2[0]);
        float u3 = m3(sA2[1], sA2[2], sA2[3]);
        float u4 = m3(sA3[0], sA3[1], sA3[2]);
        float tmA = fmaxf(m3(u0, u1, u2), m3(u3, u4, sA3[3]));
        float v0 = m3(sB0[0], sB0[1], sB0[2]);
        float v1 = m3(sB0[3], sB1[0], sB1[1]);
        float v2 = m3(sB1[2], sB1[3], sB2[0]);
        float v3 = m3(sB2[1], sB2[2], sB2[3]);
        float v4 = m3(sB3[0], sB3[1], sB3[2]);
        float tmB = fmaxf(m3(v0, v1, v2), m3(v3, v4, sB3[3]));
        tmA = fmaxf(tmA, __shfl_xor(tmA, 16, 64));
        tmA = fmaxf(tmA, __shfl_xor(tmA, 32, 64));
        tmB = fmaxf(tmB, __shfl_xor(tmB, 16, 64));
        tmB = fmaxf(tmB, __shfl_xor(tmB, 32, 64));
        if (!__all(tmA <= mA + 8.0f && tmB <= mB + 8.0f)) {
            float mnA = fmaxf(mA, tmA), mnB = fmaxf(mB, tmB);
            float cA = __builtin_amdgcn_exp2f(mA - mnA);
            float cB = __builtin_amdgcn_exp2f(mB - mnB);
            lA *= cA; lB *= cB;
            #pragma unroll
            for (int dt = 0; dt < 4; ++dt)
                #pragma unroll
                for (int r = 0; r < 4; ++r) { oA[dt][r] *= cA; oB[dt][r] *= cB; }
            mA = mnA; mB = mnB;
        }
        float pA[16], pB[16];
        #pragma unroll
        for (int r = 0; r < 4; ++r) {
            pA[r]      = __builtin_amdgcn_exp2f(sA0[r] - mA);
            pA[4 + r]  = __builtin_amdgcn_exp2f(sA1[r] - mA);
            pA[8 + r]  = __builtin_amdgcn_exp2f(sA2[r] - mA);
            pA[12 + r] = __builtin_amdgcn_exp2f(sA3[r] - mA);
            pB[r]      = __builtin_amdgcn_exp2f(sB0[r] - mB);
            pB[4 + r]  = __builtin_amdgcn_exp2f(sB1[r] - mB);
            pB[8 + r]  = __builtin_amdgcn_exp2f(sB2[r] - mB);
            pB[12 + r] = __builtin_amdgcn_exp2f(sB3[r] - mB);
        }
        float rsA = 0.f, rsB = 0.f;
        #pragma unroll
        for (int j = 0; j < 16; ++j) { rsA += pA[j]; rsB += pB[j]; }
        lA += rsA; lB += rsB;

        bf16x8 pfA0, pfA1, pfB0, pfB1;
        #pragma unroll
        for (int j = 0; j < 8; ++j) {
            pfA0[j] = (__bf16)pA[j]; pfA1[j] = (__bf16)pA[8 + j];
            pfB0[j] = (__bf16)pB[j]; pfB1[j] = (__bf16)pB[8 + j];
        }

        __builtin_amdgcn_s_setprio(1);
        #pragma unroll
        for (int dt = 0; dt < 4; ++dt) {
            bf16x8 vf0 = *(const bf16x8*)(vb + dt * 2048 + o0);
            bf16x8 vf1 = *(const bf16x8*)(vb + dt * 2048 + o4);
            oA[dt] = __builtin_amdgcn_mfma_f32_16x16x32_bf16(vf0, pfA0, oA[dt], 0, 0, 0);
            oA[dt] = __builtin_amdgcn_mfma_f32_16x16x32_bf16(vf1, pfA1, oA[dt], 0, 0, 0);
            oB[dt] = __builtin_amdgcn_mfma_f32_16x16x32_bf16(vf0, pfB0, oB[dt], 0, 0, 0);
            oB[dt] = __builtin_amdgcn_mfma_f32_16x16x32_bf16(vf1, pfB1, oB[dt], 0, 0, 0);
        }
        __builtin_amdgcn_s_setprio(0);
        cur ^= 1;
    }

    lA += __shfl_xor(lA, 16, 64); lA += __shfl_xor(lA, 32, 64);
    lB += __shfl_xor(lB, 16, 64); lB += __shfl_xor(lB, 32, 64);

    const size_t zoff = (size_t)z * (32 * 2048 * 64);
    float* opA = opart + zoff + ((size_t)bh * 2048 + q0 + lrow) * 64;
    float* opB = opart + zoff + ((size_t)bh * 2048 + q0 + 16 + lrow) * 64;
    #pragma unroll
    for (int dt = 0; dt < 4; ++dt) {
        *(f32x4*)(opA + dt * 16 + lhi * 4) = oA[dt];
        *(f32x4*)(opB + dt * 16 + lhi * 4) = oB[dt];
    }
    if (lhi == 0) {
        float* mlA = ml + ((size_t)z * (32 * 2048) + (size_t)bh * 2048 + q0 + lrow) * 2;
        float* mlB = ml + ((size_t)z * (32 * 2048) + (size_t)bh * 2048 + q0 + 16 + lrow) * 2;
        mlA[0] = mA; mlA[1] = lA;
        mlB[0] = mB; mlB[1] = lB;
    }
}

// ---------------------------------------------------------------------------
// combine two kv-half partials -> bf16 attn output [4096][1024]
__global__ __launch_bounds__(256)
void attn_combine(const float* __restrict__ opart, const float* __restrict__ ml,
                  __bf16* __restrict__ out) {
    const int idx = blockIdx.x * 256 + threadIdx.x;  // 1,048,576 total
    const int d4 = idx & 15;
    const int qrow = (idx >> 4) & 2047;
    const int bh = idx >> 15;

    const size_t row = (size_t)bh * 2048 + qrow;
    const float2 ml0 = *(const float2*)(ml + row * 2);
    const float2 ml1 = *(const float2*)(ml + ((size_t)(32 * 2048) + row) * 2);
    const f32x4 o0 = *(const f32x4*)(opart + row * 64 + d4 * 4);
    const f32x4 o1 = *(const f32x4*)(opart + (size_t)(32 * 2048 * 64) + row * 64 + d4 * 4);

    float M = fmaxf(ml0.x, ml1.x);
    float w0 = __builtin_amdgcn_exp2f(ml0.x - M);
    float w1 = __builtin_amdgcn_exp2f(ml1.x - M);
    float inv = __builtin_amdgcn_rcpf(ml0.y * w0 + ml1.y * w1);

    const int b = bh >> 4, h = bh & 15;
    bf16x4 ov;
    #pragma unroll
    for (int r = 0; r < 4; ++r)
        ov[r] = (__bf16)((o0[r] * w0 + o1[r] * w1) * inv);
    *(bf16x4*)(out + ((size_t)(b * 2048 + qrow)) * 1024 + h * 64 + d4 * 4) = ov;
}

// ---------------------------------------------------------------------------
extern "C" void kernel_launch(void* const* d_in, const int* in_sizes, int n_in,
                              void* d_out, int out_size, void* d_ws, size_t ws_size,
                              hipStream_t stream) {
    const float* x      = (const float*)d_in[0];
    const float* w_qkv  = (const float*)d_in[1];
    const float* b_qkv  = (const float*)d_in[2];
    const float* w_proj = (const float*)d_in[3];
    const float* b_proj = (const float*)d_in[4];
    float* out = (float*)d_out;

    __bf16* ws     = (__bf16*)d_ws;
    __bf16* x_bf   = ws;                          // 4096*1024        (8.4 MB)
    __bf16* wqkvT  = x_bf + 4096 * 1024;          // 3072*1024        (6.3 MB)
    __bf16* wprojT = wqkvT + 3072 * 1024;         // 1024*1024        (2.1 MB)
    __bf16* qb     = wprojT + 1024 * 1024;        // 32*2048*64
    __bf16* kb     = qb + 32 * 2048 * 64;
    __bf16* vtb    = kb + 32 * 2048 * 64;         // sigma-interleaved V^T
    __bf16* attn   = vtb + 32 * 2048 * 64;        // 4096*1024
    float*  opart  = (float*)(attn + 4096 * 1024);        // 2*32*2048*64 f32 (33.6 MB)
    float*  mlbuf  = opart + 2 * 32 * 2048 * 64;          // 2*32*2048*2  f32 (1 MB)

    const size_t need = (size_t)(mlbuf + 2 * 32 * 2048 * 2 - (float*)d_ws) * 4 / 1;
    // need is in float-element units times 4? compute directly in bytes:
    const size_t need_bytes = ((char*)(mlbuf + 2 * 32 * 2048 * 2)) - ((char*)d_ws);
    (void)need;

    cvt_x<<<4096, 256, 0, stream>>>((const float4*)x, (bf16x4*)x_bf, 4096 * 1024 / 4);
    tconv<<<dim3(96, 32), dim3(32, 8), 0, stream>>>(w_qkv, wqkvT, 1024, 3072);
    tconv<<<dim3(32, 32), dim3(32, 8), 0, stream>>>(w_proj, wprojT, 1024, 1024);
    gemm128<0><<<dim3(24, 32), 256, 0, stream>>>(x_bf, wqkvT, b_qkv, qb, 4096, 3072, 1024);

    if (ws_size >= need_bytes) {
        attn_part<<<dim3(16, 32, 2), 256, 0, stream>>>(qb, kb, vtb, opart, mlbuf);
        attn_combine<<<4096, 256, 0, stream>>>(opart, mlbuf, attn);
    } else {
        attn_fwd<<<dim3(16, 32), 256, 0, stream>>>(qb, kb, vtb, attn);
    }

    gemm128<1><<<dim3(8, 32), 256, 0, stream>>>(attn, wprojT, b_proj, out, 4096, 1024, 1024);
}

// Round 7
// 209.491 us; speedup vs baseline: 1.0929x; 1.0929x over previous
//
#include <hip/hip_runtime.h>
#include <hip/hip_bf16.h>
#include <stdint.h>

typedef __attribute__((ext_vector_type(8))) __bf16 bf16x8;
typedef __attribute__((ext_vector_type(4))) __bf16 bf16x4;
typedef __attribute__((ext_vector_type(4))) float f32x4;

#define AS1 __attribute__((address_space(1)))
#define AS3 __attribute__((address_space(3)))

__device__ __forceinline__ void load_lds16(const void* g, void* l) {
    __builtin_amdgcn_global_load_lds((const AS1 void*)g, (AS3 void*)l, 16, 0, 0);
}

__device__ __forceinline__ float m3(float a, float b, float c) {
    return fmaxf(fmaxf(a, b), c);  // clang fuses to v_max3_f32
}

constexpr float QSCALE = 0.18033688011112042f;  // 64^-0.5 * log2(e)

// sigma: storage position of kv (0..31) within a 32-column block of Vt,
// chosen so the PV B-operand slots match the P-register slots (phi mapping).
__device__ __forceinline__ int sigma32(int kv) {
    return (kv < 16) ? ((kv >> 2) * 8 + (kv & 3))
                     : (((kv - 16) >> 2) * 8 + 4 + ((kv - 16) & 3));
}

// ---------------------------------------------------------------------------
__global__ void cvt_x(const float4* __restrict__ x, bf16x4* __restrict__ o, int n4) {
    int i = blockIdx.x * blockDim.x + threadIdx.x;
    if (i >= n4) return;
    float4 v = x[i];
    bf16x4 r;
    r[0] = (__bf16)v.x; r[1] = (__bf16)v.y; r[2] = (__bf16)v.z; r[3] = (__bf16)v.w;
    o[i] = r;
}

// ---------------------------------------------------------------------------
__global__ void tconv(const float* __restrict__ src, __bf16* __restrict__ dst,
                      int R, int C) {
    __shared__ float tile[32][33];
    int c0 = blockIdx.x * 32, r0 = blockIdx.y * 32;
    int tx = threadIdx.x, ty = threadIdx.y;  // 32 x 8
    #pragma unroll
    for (int i = 0; i < 32; i += 8)
        tile[ty + i][tx] = src[(size_t)(r0 + ty + i) * C + c0 + tx];
    __syncthreads();
    #pragma unroll
    for (int i = 0; i < 32; i += 8)
        dst[(size_t)(c0 + ty + i) * R + r0 + tx] = (__bf16)tile[tx][ty + i];
}

// ---------------------------------------------------------------------------
// 128x128 bf16 GEMM, Bt is [N][K]. C = A @ Bt^T + bias.
// 2-phase double-buffered: prefetch tile k+1 via global_load_lds while
// computing tile k; ONE __syncthreads per K-step (its vmcnt(0) drain lands
// after the ds_read+MFMA phase covers the load latency).
// MODE 0: scatter Q (pre-scaled by QSCALE), K into [bh][n][d]; V transposed+
//         sigma-interleaved into Vt [bh][d][n'].  outp = q base.
// MODE 1: plain fp32 [M][Nn] output
template <int MODE>
__global__ __launch_bounds__(256)
void gemm128(const __bf16* __restrict__ A, const __bf16* __restrict__ Bt,
             const float* __restrict__ bias, void* __restrict__ outp,
             int M, int Nn, int K) {
    __shared__ __bf16 As[2][128][32];
    __shared__ __bf16 Bs[2][128][32];
    const int t = threadIdx.x;
    const int w = t >> 6, l = t & 63;
    const int lrow = l & 15, lhi = l >> 4;
    const int wr = (w >> 1) * 64, wc = (w & 1) * 64;
    const int m0 = blockIdx.y * 128, n0 = blockIdx.x * 128;

    f32x4 acc[4][4] = {};

    const int sr = t >> 2, sc = (t & 3) * 8;
    const __bf16* ag = A + (size_t)(m0 + sr) * K + sc;
    const __bf16* bg = Bt + (size_t)(n0 + sr) * K + sc;

    // prologue: stage tile 0 into buf 0
    load_lds16(ag, &As[0][sr][sc]);
    load_lds16(ag + (size_t)64 * K, &As[0][64 + sr][sc]);
    load_lds16(bg, &Bs[0][sr][sc]);
    load_lds16(bg + (size_t)64 * K, &Bs[0][64 + sr][sc]);
    ag += 32; bg += 32;
    __syncthreads();

    int cur = 0;
    for (int kt = 0; kt < K; kt += 32) {
        if (kt + 32 < K) {  // prefetch next tile into the other buffer
            load_lds16(ag, &As[cur ^ 1][sr][sc]);
            load_lds16(ag + (size_t)64 * K, &As[cur ^ 1][64 + sr][sc]);
            load_lds16(bg, &Bs[cur ^ 1][sr][sc]);
            load_lds16(bg + (size_t)64 * K, &Bs[cur ^ 1][64 + sr][sc]);
            ag += 32; bg += 32;
        }
        bf16x8 af[4], bfv[4];
        #pragma unroll
        for (int i = 0; i < 4; ++i)
            af[i] = *(const bf16x8*)(&As[cur][wr + i * 16 + lrow][lhi * 8]);
        #pragma unroll
        for (int j = 0; j < 4; ++j)
            bfv[j] = *(const bf16x8*)(&Bs[cur][wc + j * 16 + lrow][lhi * 8]);
        #pragma unroll
        for (int i = 0; i < 4; ++i)
            #pragma unroll
            for (int j = 0; j < 4; ++j)
                acc[i][j] = __builtin_amdgcn_mfma_f32_16x16x32_bf16(
                    af[i], bfv[j], acc[i][j], 0, 0, 0);
        __syncthreads();  // drains prefetch vmcnt + orders buffer reuse
        cur ^= 1;
    }

    #pragma unroll
    for (int i = 0; i < 4; ++i)
        #pragma unroll
        for (int j = 0; j < 4; ++j)
            #pragma unroll
            for (int r = 0; r < 4; ++r) {
                int row = m0 + wr + i * 16 + lhi * 4 + r;
                int col = n0 + wc + j * 16 + lrow;
                float val = acc[i][j][r] + bias[col];
                if (MODE == 0) {
                    int which = col >> 10;          // 0=q 1=k 2=v
                    int h = (col >> 6) & 15;
                    int d = col & 63;
                    int b = row >> 11;
                    int n = row & 2047;
                    int bh = (b << 4) + h;
                    if (which == 2) {
                        ((__bf16*)outp)[(size_t)2 * (32 * 2048 * 64) +
                                        ((size_t)bh * 64 + d) * 2048 +
                                        (n & ~31) + sigma32(n & 31)] = (__bf16)val;
                    } else {
                        if (which == 0) val *= QSCALE;
                        ((__bf16*)outp)[(size_t)which * (32 * 2048 * 64) +
                                        ((size_t)bh * 2048 + n) * 64 + d] = (__bf16)val;
                    }
                } else {
                    ((float*)outp)[(size_t)row * Nn + col] = val;
                }
            }
}

// ---------------------------------------------------------------------------
// flash attention, swapped-QK^T, in-register P, swizzled K/V LDS, KVBLK=64.
// Each wave owns 32 q-rows (2 groups of 16 sharing K/V fragments).
// q,k: [32][2048][64] (q pre-scaled)   vt: [32][64][2048] sigma-interleaved
// out: [4096][1024] bf16
__global__ __launch_bounds__(256)
void attn_fwd(const __bf16* __restrict__ q, const __bf16* __restrict__ k,
              const __bf16* __restrict__ vt, __bf16* __restrict__ out) {
    __shared__ __bf16 KsV[2][64][64];
    __shared__ __bf16 VsV[2][64][64];
    char* ksB = (char*)KsV;
    char* vsB = (char*)VsV;

    const int t = threadIdx.x;
    const int w = t >> 6, l = t & 63;
    const int lrow = l & 15, lhi = l >> 4;
    const int bh = blockIdx.y;
    const int q0 = blockIdx.x * 128 + w * 32;

    const __bf16* qp = q + ((size_t)bh * 2048 + q0) * 64;
    bf16x8 qfA0 = *(const bf16x8*)(qp + lrow * 64 + lhi * 8);
    bf16x8 qfA1 = *(const bf16x8*)(qp + lrow * 64 + 32 + lhi * 8);
    bf16x8 qfB0 = *(const bf16x8*)(qp + (16 + lrow) * 64 + lhi * 8);
    bf16x8 qfB1 = *(const bf16x8*)(qp + (16 + lrow) * 64 + 32 + lhi * 8);

    f32x4 oA[4] = {}, oB[4] = {};
    float mA = -1e30f, mB = -1e30f;
    float lA = 0.f, lB = 0.f;

    const __bf16* kg = k + (size_t)bh * 2048 * 64;
    const __bf16* vg = vt + (size_t)bh * 64 * 2048;

    const int sr = t >> 3;
    const int sw8 = ((t & 7) ^ (sr & 7)) * 8;
    const int rsw = (lrow & 7) << 4;

    {
        char* kd = ksB + t * 16;
        char* vd = vsB + t * 16;
        load_lds16(kg + (size_t)sr * 64 + sw8, kd);
        load_lds16(kg + (size_t)(32 + sr) * 64 + sw8, kd + 4096);
        load_lds16(vg + (size_t)sr * 2048 + sw8, vd);
        load_lds16(vg + (size_t)(32 + sr) * 2048 + sw8, vd + 4096);
    }

    const __bf16* kst  = kg + (size_t)(64 + sr) * 64 + sw8;
    const __bf16* kst2 = kst + 32 * 64;
    const __bf16* vst  = vg + (size_t)sr * 2048 + 64 + sw8;
    const __bf16* vst2 = vst + 32 * 2048;

    int cur = 0;
    for (int kv0 = 0; kv0 < 2048; kv0 += 64) {
        __syncthreads();
        if (kv0 + 64 < 2048) {
            char* kd = ksB + (cur ^ 1) * 8192 + t * 16;
            char* vd = vsB + (cur ^ 1) * 8192 + t * 16;
            load_lds16(kst, kd);
            load_lds16(kst2, kd + 4096);
            load_lds16(vst, vd);
            load_lds16(vst2, vd + 4096);
            kst += 4096; kst2 += 4096; vst += 64; vst2 += 64;
        }
        const char* kb = ksB + cur * 8192 + lrow * 128;
        const char* vb = vsB + cur * 8192 + lrow * 128;
        const int o0 = (lhi << 4) ^ rsw;
        const int o4 = ((4 + lhi) << 4) ^ rsw;

        f32x4 sA0 = {}, sA1 = {}, sA2 = {}, sA3 = {};
        f32x4 sB0 = {}, sB1 = {}, sB2 = {}, sB3 = {};
        __builtin_amdgcn_s_setprio(1);
        {
            bf16x8 kf0, kf1;
#define QK_GROUP(SA, SB, BASE)                                                 \
            kf0 = *(const bf16x8*)(kb + (BASE) + o0);                          \
            kf1 = *(const bf16x8*)(kb + (BASE) + o4);                          \
            SA = __builtin_amdgcn_mfma_f32_16x16x32_bf16(kf0, qfA0, SA, 0, 0, 0); \
            SA = __builtin_amdgcn_mfma_f32_16x16x32_bf16(kf1, qfA1, SA, 0, 0, 0); \
            SB = __builtin_amdgcn_mfma_f32_16x16x32_bf16(kf0, qfB0, SB, 0, 0, 0); \
            SB = __builtin_amdgcn_mfma_f32_16x16x32_bf16(kf1, qfB1, SB, 0, 0, 0);
            QK_GROUP(sA0, sB0, 0)
            QK_GROUP(sA1, sB1, 2048)
            QK_GROUP(sA2, sB2, 4096)
            QK_GROUP(sA3, sB3, 6144)
#undef QK_GROUP
        }
        __builtin_amdgcn_s_setprio(0);

        float u0 = m3(sA0[0], sA0[1], sA0[2]);
        float u1 = m3(sA0[3], sA1[0], sA1[1]);
        float u2 = m3(sA1[2], sA1[3], sA2[0]);
        float u3 = m3(sA2[1], sA2[2], sA2[3]);
        float u4 = m3(sA3[0], sA3[1], sA3[2]);
        float tmA = fmaxf(m3(u0, u1, u2), m3(u3, u4, sA3[3]));
        float v0 = m3(sB0[0], sB0[1], sB0[2]);
        float v1 = m3(sB0[3], sB1[0], sB1[1]);
        float v2 = m3(sB1[2], sB1[3], sB2[0]);
        float v3 = m3(sB2[1], sB2[2], sB2[3]);
        float v4 = m3(sB3[0], sB3[1], sB3[2]);
        float tmB = fmaxf(m3(v0, v1, v2), m3(v3, v4, sB3[3]));
        tmA = fmaxf(tmA, __shfl_xor(tmA, 16, 64));
        tmA = fmaxf(tmA, __shfl_xor(tmA, 32, 64));
        tmB = fmaxf(tmB, __shfl_xor(tmB, 16, 64));
        tmB = fmaxf(tmB, __shfl_xor(tmB, 32, 64));
        if (!__all(tmA <= mA + 8.0f && tmB <= mB + 8.0f)) {
            float mnA = fmaxf(mA, tmA), mnB = fmaxf(mB, tmB);
            float cA = __builtin_amdgcn_exp2f(mA - mnA);
            float cB = __builtin_amdgcn_exp2f(mB - mnB);
            lA *= cA; lB *= cB;
            #pragma unroll
            for (int dt = 0; dt < 4; ++dt)
                #pragma unroll
                for (int r = 0; r < 4; ++r) { oA[dt][r] *= cA; oB[dt][r] *= cB; }
            mA = mnA; mB = mnB;
        }
        float pA[16], pB[16];
        #pragma unroll
        for (int r = 0; r < 4; ++r) {
            pA[r]      = __builtin_amdgcn_exp2f(sA0[r] - mA);
            pA[4 + r]  = __builtin_amdgcn_exp2f(sA1[r] - mA);
            pA[8 + r]  = __builtin_amdgcn_exp2f(sA2[r] - mA);
            pA[12 + r] = __builtin_amdgcn_exp2f(sA3[r] - mA);
            pB[r]      = __builtin_amdgcn_exp2f(sB0[r] - mB);
            pB[4 + r]  = __builtin_amdgcn_exp2f(sB1[r] - mB);
            pB[8 + r]  = __builtin_amdgcn_exp2f(sB2[r] - mB);
            pB[12 + r] = __builtin_amdgcn_exp2f(sB3[r] - mB);
        }
        float rsA = 0.f, rsB = 0.f;
        #pragma unroll
        for (int j = 0; j < 16; ++j) { rsA += pA[j]; rsB += pB[j]; }
        lA += rsA; lB += rsB;

        bf16x8 pfA0, pfA1, pfB0, pfB1;
        #pragma unroll
        for (int j = 0; j < 8; ++j) {
            pfA0[j] = (__bf16)pA[j]; pfA1[j] = (__bf16)pA[8 + j];
            pfB0[j] = (__bf16)pB[j]; pfB1[j] = (__bf16)pB[8 + j];
        }

        __builtin_amdgcn_s_setprio(1);
        #pragma unroll
        for (int dt = 0; dt < 4; ++dt) {
            bf16x8 vf0 = *(const bf16x8*)(vb + dt * 2048 + o0);
            bf16x8 vf1 = *(const bf16x8*)(vb + dt * 2048 + o4);
            oA[dt] = __builtin_amdgcn_mfma_f32_16x16x32_bf16(vf0, pfA0, oA[dt], 0, 0, 0);
            oA[dt] = __builtin_amdgcn_mfma_f32_16x16x32_bf16(vf1, pfA1, oA[dt], 0, 0, 0);
            oB[dt] = __builtin_amdgcn_mfma_f32_16x16x32_bf16(vf0, pfB0, oB[dt], 0, 0, 0);
            oB[dt] = __builtin_amdgcn_mfma_f32_16x16x32_bf16(vf1, pfB1, oB[dt], 0, 0, 0);
        }
        __builtin_amdgcn_s_setprio(0);
        cur ^= 1;
    }

    lA += __shfl_xor(lA, 16, 64); lA += __shfl_xor(lA, 32, 64);
    lB += __shfl_xor(lB, 16, 64); lB += __shfl_xor(lB, 32, 64);
    float invA = __builtin_amdgcn_rcpf(lA);
    float invB = __builtin_amdgcn_rcpf(lB);

    const int b = bh >> 4, h = bh & 15;
    __bf16* orowA = out + ((size_t)(b * 2048 + q0 + lrow)) * 1024 + h * 64;
    __bf16* orowB = out + ((size_t)(b * 2048 + q0 + 16 + lrow)) * 1024 + h * 64;
    #pragma unroll
    for (int dt = 0; dt < 4; ++dt) {
        bf16x4 ovA, ovB;
        #pragma unroll
        for (int r = 0; r < 4; ++r) {
            ovA[r] = (__bf16)(oA[dt][r] * invA);
            ovB[r] = (__bf16)(oB[dt][r] * invB);
        }
        *(bf16x4*)(orowA + dt * 16 + lhi * 4) = ovA;
        *(bf16x4*)(orowB + dt * 16 + lhi * 4) = ovB;
    }
}

// ---------------------------------------------------------------------------
extern "C" void kernel_launch(void* const* d_in, const int* in_sizes, int n_in,
                              void* d_out, int out_size, void* d_ws, size_t ws_size,
                              hipStream_t stream) {
    const float* x      = (const float*)d_in[0];
    const float* w_qkv  = (const float*)d_in[1];
    const float* b_qkv  = (const float*)d_in[2];
    const float* w_proj = (const float*)d_in[3];
    const float* b_proj = (const float*)d_in[4];
    float* out = (float*)d_out;

    __bf16* ws     = (__bf16*)d_ws;
    __bf16* x_bf   = ws;                          // 4096*1024
    __bf16* wqkvT  = x_bf + 4096 * 1024;          // 3072*1024
    __bf16* wprojT = wqkvT + 3072 * 1024;         // 1024*1024
    __bf16* qb     = wprojT + 1024 * 1024;        // 32*2048*64
    __bf16* kb     = qb + 32 * 2048 * 64;
    __bf16* vtb    = kb + 32 * 2048 * 64;         // sigma-interleaved V^T
    __bf16* attn   = vtb + 32 * 2048 * 64;        // 4096*1024

    cvt_x<<<4096, 256, 0, stream>>>((const float4*)x, (bf16x4*)x_bf, 4096 * 1024 / 4);
    tconv<<<dim3(96, 32), dim3(32, 8), 0, stream>>>(w_qkv, wqkvT, 1024, 3072);
    tconv<<<dim3(32, 32), dim3(32, 8), 0, stream>>>(w_proj, wprojT, 1024, 1024);
    gemm128<0><<<dim3(24, 32), 256, 0, stream>>>(x_bf, wqkvT, b_qkv, qb, 4096, 3072, 1024);
    attn_fwd<<<dim3(16, 32), 256, 0, stream>>>(qb, kb, vtb, attn);
    gemm128<1><<<dim3(8, 32), 256, 0, stream>>>(attn, wprojT, b_proj, out, 4096, 1024, 1024);
}

// Round 9
// 208.530 us; speedup vs baseline: 1.0979x; 1.0046x over previous
//
#include <hip/hip_runtime.h>
#include <hip/hip_bf16.h>
#include <stdint.h>

typedef __attribute__((ext_vector_type(8))) __bf16 bf16x8;
typedef __attribute__((ext_vector_type(4))) __bf16 bf16x4;
typedef __attribute__((ext_vector_type(4))) float f32x4;

#define AS1 __attribute__((address_space(1)))
#define AS3 __attribute__((address_space(3)))

__device__ __forceinline__ void load_lds16(const void* g, void* l) {
    __builtin_amdgcn_global_load_lds((const AS1 void*)g, (AS3 void*)l, 16, 0, 0);
}

__device__ __forceinline__ float m3(float a, float b, float c) {
    return fmaxf(fmaxf(a, b), c);  // clang fuses to v_max3_f32
}

constexpr float QSCALE = 0.18033688011112042f;  // 64^-0.5 * log2(e)

// sigma: storage position of kv (0..31) within a 32-column block of Vt,
// chosen so the PV B-operand slots match the P-register slots (phi mapping).
__device__ __forceinline__ int sigma32(int kv) {
    return (kv < 16) ? ((kv >> 2) * 8 + (kv & 3))
                     : (((kv - 16) >> 2) * 8 + 4 + ((kv - 16) & 3));
}

// ---------------------------------------------------------------------------
__global__ void cvt_x(const float4* __restrict__ x, bf16x4* __restrict__ o, int n4) {
    int i = blockIdx.x * blockDim.x + threadIdx.x;
    if (i >= n4) return;
    float4 v = x[i];
    bf16x4 r;
    r[0] = (__bf16)v.x; r[1] = (__bf16)v.y; r[2] = (__bf16)v.z; r[3] = (__bf16)v.w;
    o[i] = r;
}

// ---------------------------------------------------------------------------
__global__ void tconv(const float* __restrict__ src, __bf16* __restrict__ dst,
                      int R, int C) {
    __shared__ float tile[32][33];
    int c0 = blockIdx.x * 32, r0 = blockIdx.y * 32;
    int tx = threadIdx.x, ty = threadIdx.y;  // 32 x 8
    #pragma unroll
    for (int i = 0; i < 32; i += 8)
        tile[ty + i][tx] = src[(size_t)(r0 + ty + i) * C + c0 + tx];
    __syncthreads();
    #pragma unroll
    for (int i = 0; i < 32; i += 8)
        dst[(size_t)(c0 + ty + i) * R + r0 + tx] = (__bf16)tile[tx][ty + i];
}

// ---------------------------------------------------------------------------
// 128x128 bf16 GEMM, Bt is [N][K]. C = A @ Bt^T + bias.
// Depth-2 counted-vmcnt pipeline: 3 LDS buffers; prefetch tiles t+1,t+2;
// per K-step: STAGE(t+2) -> s_waitcnt vmcnt(8) (tile-t done, t+1/t+2 in
// flight) -> s_barrier -> ds_read+MFMA -> lgkmcnt(0)+s_barrier (WAR guard).
// Chunk-XOR swizzle (c ^= (row>>1)&3 per 16B chunk): write side folded into
// the pre-swizzled GLOBAL source (LDS dest stays linear, rule #21); read
// side applies the same XOR. 8-way -> 2-way bank aliasing on ds_read_b128.
// MODE 0: scatter Q (pre-scaled), K into [bh][n][d]; V -> sigma-interleaved
//         Vt [bh][d][n'].  MODE 1: plain fp32 [M][Nn] output.
template <int MODE>
__global__ __launch_bounds__(256)
void gemm128(const __bf16* __restrict__ A, const __bf16* __restrict__ Bt,
             const float* __restrict__ bias, void* __restrict__ outp,
             int M, int Nn, int K) {
    __shared__ __bf16 As[3][128][32];
    __shared__ __bf16 Bs[3][128][32];
    const int t = threadIdx.x;
    const int w = t >> 6, l = t & 63;
    const int lrow = l & 15, lhi = l >> 4;
    const int wr = (w >> 1) * 64, wc = (w & 1) * 64;

    // XCD-aware block swizzle (T1): contiguous tile chunk per XCD
    int nwg = gridDim.x * gridDim.y;
    int flat = blockIdx.x + blockIdx.y * gridDim.x;
    if ((nwg & 7) == 0) flat = (flat & 7) * (nwg >> 3) + (flat >> 3);
    const int m0 = (flat / gridDim.x) * 128;
    const int n0 = (flat % gridDim.x) * 128;

    f32x4 acc[4][4] = {};

    // staging: thread t -> row sr, linear dest chunk (t&3); source chunk
    // XOR-swizzled so physical chunk p holds semantic chunk p^((r>>1)&3)
    const int sr = t >> 2;
    const int dc = (t & 3) * 8;                          // dest elems (linear)
    const int scsw = ((t & 3) ^ ((sr >> 1) & 3)) * 8;    // swizzled src elems
    const __bf16* agb = A + (size_t)(m0 + sr) * K + scsw;
    const __bf16* bgb = Bt + (size_t)(n0 + sr) * K + scsw;

#define STAGE_G(BUF, KT)                                                   \
    { load_lds16(agb + (KT), &As[BUF][sr][dc]);                            \
      load_lds16(agb + (size_t)64 * K + (KT), &As[BUF][64 + sr][dc]);      \
      load_lds16(bgb + (KT), &Bs[BUF][sr][dc]);                            \
      load_lds16(bgb + (size_t)64 * K + (KT), &Bs[BUF][64 + sr][dc]); }

    STAGE_G(0, 0)
    STAGE_G(1, 32)

    const int rofs = (lhi ^ ((lrow >> 1) & 3)) << 4;     // read-side swizzle (bytes)
    const int nt = K >> 5;
    int cur = 0, pre = 2;
    for (int tt = 0; tt < nt; ++tt) {
        if (tt + 2 < nt) {
            STAGE_G(pre, (tt + 2) * 32)
            asm volatile("s_waitcnt vmcnt(8)" ::: "memory");
        } else if (tt + 1 < nt) {
            asm volatile("s_waitcnt vmcnt(4)" ::: "memory");
        } else {
            asm volatile("s_waitcnt vmcnt(0)" ::: "memory");
        }
        __builtin_amdgcn_sched_barrier(0);
        __builtin_amdgcn_s_barrier();        // all waves: tile tt fully in LDS
        __builtin_amdgcn_sched_barrier(0);

        bf16x8 af[4], bfv[4];
        #pragma unroll
        for (int i = 0; i < 4; ++i)
            af[i] = *(const bf16x8*)((const char*)&As[cur][wr + i * 16 + lrow][0] + rofs);
        #pragma unroll
        for (int j = 0; j < 4; ++j)
            bfv[j] = *(const bf16x8*)((const char*)&Bs[cur][wc + j * 16 + lrow][0] + rofs);
        __builtin_amdgcn_s_setprio(1);
        #pragma unroll
        for (int i = 0; i < 4; ++i)
            #pragma unroll
            for (int j = 0; j < 4; ++j)
                acc[i][j] = __builtin_amdgcn_mfma_f32_16x16x32_bf16(
                    af[i], bfv[j], acc[i][j], 0, 0, 0);
        __builtin_amdgcn_s_setprio(0);

        __builtin_amdgcn_sched_barrier(0);
        asm volatile("s_waitcnt lgkmcnt(0)" ::: "memory");  // reads of buf[cur] done
        __builtin_amdgcn_s_barrier();        // WAR: before buf[cur] is re-staged
        __builtin_amdgcn_sched_barrier(0);

        cur = (cur == 2) ? 0 : cur + 1;
        pre = (pre == 2) ? 0 : pre + 1;
    }
#undef STAGE_G

    #pragma unroll
    for (int i = 0; i < 4; ++i)
        #pragma unroll
        for (int j = 0; j < 4; ++j)
            #pragma unroll
            for (int r = 0; r < 4; ++r) {
                int row = m0 + wr + i * 16 + lhi * 4 + r;
                int col = n0 + wc + j * 16 + lrow;
                float val = acc[i][j][r] + bias[col];
                if (MODE == 0) {
                    int which = col >> 10;          // 0=q 1=k 2=v
                    int h = (col >> 6) & 15;
                    int d = col & 63;
                    int b = row >> 11;
                    int n = row & 2047;
                    int bh = (b << 4) + h;
                    if (which == 2) {
                        ((__bf16*)outp)[(size_t)2 * (32 * 2048 * 64) +
                                        ((size_t)bh * 64 + d) * 2048 +
                                        (n & ~31) + sigma32(n & 31)] = (__bf16)val;
                    } else {
                        if (which == 0) val *= QSCALE;
                        ((__bf16*)outp)[(size_t)which * (32 * 2048 * 64) +
                                        ((size_t)bh * 2048 + n) * 64 + d] = (__bf16)val;
                    }
                } else {
                    ((float*)outp)[(size_t)row * Nn + col] = val;
                }
            }
}

// ---------------------------------------------------------------------------
// flash attention, swapped-QK^T, in-register P, swizzled K/V LDS, KVBLK=64.
// Each wave owns 32 q-rows (2 groups of 16 sharing K/V fragments).
// q,k: [32][2048][64] (q pre-scaled)   vt: [32][64][2048] sigma-interleaved
// out: [4096][1024] bf16
__global__ __launch_bounds__(256)
void attn_fwd(const __bf16* __restrict__ q, const __bf16* __restrict__ k,
              const __bf16* __restrict__ vt, __bf16* __restrict__ out) {
    __shared__ __bf16 KsV[2][64][64];
    __shared__ __bf16 VsV[2][64][64];
    char* ksB = (char*)KsV;
    char* vsB = (char*)VsV;

    const int t = threadIdx.x;
    const int w = t >> 6, l = t & 63;
    const int lrow = l & 15, lhi = l >> 4;
    const int bh = blockIdx.y;
    const int q0 = blockIdx.x * 128 + w * 32;

    const __bf16* qp = q + ((size_t)bh * 2048 + q0) * 64;
    bf16x8 qfA0 = *(const bf16x8*)(qp + lrow * 64 + lhi * 8);
    bf16x8 qfA1 = *(const bf16x8*)(qp + lrow * 64 + 32 + lhi * 8);
    bf16x8 qfB0 = *(const bf16x8*)(qp + (16 + lrow) * 64 + lhi * 8);
    bf16x8 qfB1 = *(const bf16x8*)(qp + (16 + lrow) * 64 + 32 + lhi * 8);

    f32x4 oA[4] = {}, oB[4] = {};
    float mA = -1e30f, mB = -1e30f;
    float lA = 0.f, lB = 0.f;

    const __bf16* kg = k + (size_t)bh * 2048 * 64;
    const __bf16* vg = vt + (size_t)bh * 64 * 2048;

    const int sr = t >> 3;
    const int sw8 = ((t & 7) ^ (sr & 7)) * 8;
    const int rsw = (lrow & 7) << 4;

    {
        char* kd = ksB + t * 16;
        char* vd = vsB + t * 16;
        load_lds16(kg + (size_t)sr * 64 + sw8, kd);
        load_lds16(kg + (size_t)(32 + sr) * 64 + sw8, kd + 4096);
        load_lds16(vg + (size_t)sr * 2048 + sw8, vd);
        load_lds16(vg + (size_t)(32 + sr) * 2048 + sw8, vd + 4096);
    }

    const __bf16* kst  = kg + (size_t)(64 + sr) * 64 + sw8;
    const __bf16* kst2 = kst + 32 * 64;
    const __bf16* vst  = vg + (size_t)sr * 2048 + 64 + sw8;
    const __bf16* vst2 = vst + 32 * 2048;

    int cur = 0;
    for (int kv0 = 0; kv0 < 2048; kv0 += 64) {
        __syncthreads();
        if (kv0 + 64 < 2048) {
            char* kd = ksB + (cur ^ 1) * 8192 + t * 16;
            char* vd = vsB + (cur ^ 1) * 8192 + t * 16;
            load_lds16(kst, kd);
            load_lds16(kst2, kd + 4096);
            load_lds16(vst, vd);
            load_lds16(vst2, vd + 4096);
            kst += 4096; kst2 += 4096; vst += 64; vst2 += 64;
        }
        const char* kb = ksB + cur * 8192 + lrow * 128;
        const char* vb = vsB + cur * 8192 + lrow * 128;
        const int o0 = (lhi << 4) ^ rsw;
        const int o4 = ((4 + lhi) << 4) ^ rsw;

        f32x4 sA0 = {}, sA1 = {}, sA2 = {}, sA3 = {};
        f32x4 sB0 = {}, sB1 = {}, sB2 = {}, sB3 = {};
        __builtin_amdgcn_s_setprio(1);
        {
            bf16x8 kf0, kf1;
#define QK_GROUP(SA, SB, BASE)                                                 \
            kf0 = *(const bf16x8*)(kb + (BASE) + o0);                          \
            kf1 = *(const bf16x8*)(kb + (BASE) + o4);                          \
            SA = __builtin_amdgcn_mfma_f32_16x16x32_bf16(kf0, qfA0, SA, 0, 0, 0); \
            SA = __builtin_amdgcn_mfma_f32_16x16x32_bf16(kf1, qfA1, SA, 0, 0, 0); \
            SB = __builtin_amdgcn_mfma_f32_16x16x32_bf16(kf0, qfB0, SB, 0, 0, 0); \
            SB = __builtin_amdgcn_mfma_f32_16x16x32_bf16(kf1, qfB1, SB, 0, 0, 0);
            QK_GROUP(sA0, sB0, 0)
            QK_GROUP(sA1, sB1, 2048)
            QK_GROUP(sA2, sB2, 4096)
            QK_GROUP(sA3, sB3, 6144)
#undef QK_GROUP
        }
        __builtin_amdgcn_s_setprio(0);

        float u0 = m3(sA0[0], sA0[1], sA0[2]);
        float u1 = m3(sA0[3], sA1[0], sA1[1]);
        float u2 = m3(sA1[2], sA1[3], sA2[0]);
        float u3 = m3(sA2[1], sA2[2], sA2[3]);
        float u4 = m3(sA3[0], sA3[1], sA3[2]);
        float tmA = fmaxf(m3(u0, u1, u2), m3(u3, u4, sA3[3]));
        float v0 = m3(sB0[0], sB0[1], sB0[2]);
        float v1 = m3(sB0[3], sB1[0], sB1[1]);
        float v2 = m3(sB1[2], sB1[3], sB2[0]);
        float v3 = m3(sB2[1], sB2[2], sB2[3]);
        float v4 = m3(sB3[0], sB3[1], sB3[2]);
        float tmB = fmaxf(m3(v0, v1, v2), m3(v3, v4, sB3[3]));
        tmA = fmaxf(tmA, __shfl_xor(tmA, 16, 64));
        tmA = fmaxf(tmA, __shfl_xor(tmA, 32, 64));
        tmB = fmaxf(tmB, __shfl_xor(tmB, 16, 64));
        tmB = fmaxf(tmB, __shfl_xor(tmB, 32, 64));
        if (!__all(tmA <= mA + 8.0f && tmB <= mB + 8.0f)) {
            float mnA = fmaxf(mA, tmA), mnB = fmaxf(mB, tmB);
            float cA = __builtin_amdgcn_exp2f(mA - mnA);
            float cB = __builtin_amdgcn_exp2f(mB - mnB);
            lA *= cA; lB *= cB;
            #pragma unroll
            for (int dt = 0; dt < 4; ++dt)
                #pragma unroll
                for (int r = 0; r < 4; ++r) { oA[dt][r] *= cA; oB[dt][r] *= cB; }
            mA = mnA; mB = mnB;
        }
        float pA[16], pB[16];
        #pragma unroll
        for (int r = 0; r < 4; ++r) {
            pA[r]      = __builtin_amdgcn_exp2f(sA0[r] - mA);
            pA[4 + r]  = __builtin_amdgcn_exp2f(sA1[r] - mA);
            pA[8 + r]  = __builtin_amdgcn_exp2f(sA2[r] - mA);
            pA[12 + r] = __builtin_amdgcn_exp2f(sA3[r] - mA);
            pB[r]      = __builtin_amdgcn_exp2f(sB0[r] - mB);
            pB[4 + r]  = __builtin_amdgcn_exp2f(sB1[r] - mB);
            pB[8 + r]  = __builtin_amdgcn_exp2f(sB2[r] - mB);
            pB[12 + r] = __builtin_amdgcn_exp2f(sB3[r] - mB);
        }
        float rsA = 0.f, rsB = 0.f;
        #pragma unroll
        for (int j = 0; j < 16; ++j) { rsA += pA[j]; rsB += pB[j]; }
        lA += rsA; lB += rsB;

        bf16x8 pfA0, pfA1, pfB0, pfB1;
        #pragma unroll
        for (int j = 0; j < 8; ++j) {
            pfA0[j] = (__bf16)pA[j]; pfA1[j] = (__bf16)pA[8 + j];
            pfB0[j] = (__bf16)pB[j]; pfB1[j] = (__bf16)pB[8 + j];
        }

        __builtin_amdgcn_s_setprio(1);
        #pragma unroll
        for (int dt = 0; dt < 4; ++dt) {
            bf16x8 vf0 = *(const bf16x8*)(vb + dt * 2048 + o0);
            bf16x8 vf1 = *(const bf16x8*)(vb + dt * 2048 + o4);
            oA[dt] = __builtin_amdgcn_mfma_f32_16x16x32_bf16(vf0, pfA0, oA[dt], 0, 0, 0);
            oA[dt] = __builtin_amdgcn_mfma_f32_16x16x32_bf16(vf1, pfA1, oA[dt], 0, 0, 0);
            oB[dt] = __builtin_amdgcn_mfma_f32_16x16x32_bf16(vf0, pfB0, oB[dt], 0, 0, 0);
            oB[dt] = __builtin_amdgcn_mfma_f32_16x16x32_bf16(vf1, pfB1, oB[dt], 0, 0, 0);
        }
        __builtin_amdgcn_s_setprio(0);
        cur ^= 1;
    }

    lA += __shfl_xor(lA, 16, 64); lA += __shfl_xor(lA, 32, 64);
    lB += __shfl_xor(lB, 16, 64); lB += __shfl_xor(lB, 32, 64);
    float invA = __builtin_amdgcn_rcpf(lA);
    float invB = __builtin_amdgcn_rcpf(lB);

    const int b = bh >> 4, h = bh & 15;
    __bf16* orowA = out + ((size_t)(b * 2048 + q0 + lrow)) * 1024 + h * 64;
    __bf16* orowB = out + ((size_t)(b * 2048 + q0 + 16 + lrow)) * 1024 + h * 64;
    #pragma unroll
    for (int dt = 0; dt < 4; ++dt) {
        bf16x4 ovA, ovB;
        #pragma unroll
        for (int r = 0; r < 4; ++r) {
            ovA[r] = (__bf16)(oA[dt][r] * invA);
            ovB[r] = (__bf16)(oB[dt][r] * invB);
        }
        *(bf16x4*)(orowA + dt * 16 + lhi * 4) = ovA;
        *(bf16x4*)(orowB + dt * 16 + lhi * 4) = ovB;
    }
}

// ---------------------------------------------------------------------------
extern "C" void kernel_launch(void* const* d_in, const int* in_sizes, int n_in,
                              void* d_out, int out_size, void* d_ws, size_t ws_size,
                              hipStream_t stream) {
    const float* x      = (const float*)d_in[0];
    const float* w_qkv  = (const float*)d_in[1];
    const float* b_qkv  = (const float*)d_in[2];
    const float* w_proj = (const float*)d_in[3];
    const float* b_proj = (const float*)d_in[4];
    float* out = (float*)d_out;

    __bf16* ws     = (__bf16*)d_ws;
    __bf16* x_bf   = ws;                          // 4096*1024
    __bf16* wqkvT  = x_bf + 4096 * 1024;          // 3072*1024
    __bf16* wprojT = wqkvT + 3072 * 1024;         // 1024*1024
    __bf16* qb     = wprojT + 1024 * 1024;        // 32*2048*64
    __bf16* kb     = qb + 32 * 2048 * 64;
    __bf16* vtb    = kb + 32 * 2048 * 64;         // sigma-interleaved V^T
    __bf16* attn   = vtb + 32 * 2048 * 64;        // 4096*1024

    cvt_x<<<4096, 256, 0, stream>>>((const float4*)x, (bf16x4*)x_bf, 4096 * 1024 / 4);
    tconv<<<dim3(96, 32), dim3(32, 8), 0, stream>>>(w_qkv, wqkvT, 1024, 3072);
    tconv<<<dim3(32, 32), dim3(32, 8), 0, stream>>>(w_proj, wprojT, 1024, 1024);
    gemm128<0><<<dim3(24, 32), 256, 0, stream>>>(x_bf, wqkvT, b_qkv, qb, 4096, 3072, 1024);
    attn_fwd<<<dim3(16, 32), 256, 0, stream>>>(qb, kb, vtb, attn);
    gemm128<1><<<dim3(8, 32), 256, 0, stream>>>(attn, wprojT, b_proj, out, 4096, 1024, 1024);
}

// Round 10
// 204.562 us; speedup vs baseline: 1.1192x; 1.0194x over previous
//
#include <hip/hip_runtime.h>
#include <hip/hip_bf16.h>
#include <stdint.h>

typedef __attribute__((ext_vector_type(8))) __bf16 bf16x8;
typedef __attribute__((ext_vector_type(4))) __bf16 bf16x4;
typedef __attribute__((ext_vector_type(4))) float f32x4;

#define AS1 __attribute__((address_space(1)))
#define AS3 __attribute__((address_space(3)))

__device__ __forceinline__ void load_lds16(const void* g, void* l) {
    __builtin_amdgcn_global_load_lds((const AS1 void*)g, (AS3 void*)l, 16, 0, 0);
}

__device__ __forceinline__ float m3(float a, float b, float c) {
    return fmaxf(fmaxf(a, b), c);  // clang fuses to v_max3_f32
}

constexpr float QSCALE = 0.18033688011112042f;  // 64^-0.5 * log2(e)

// sigma: storage position of kv (0..31) within a 32-column block of Vt,
// chosen so the PV B-operand slots match the P-register slots (phi mapping).
__device__ __forceinline__ int sigma32(int kv) {
    return (kv < 16) ? ((kv >> 2) * 8 + (kv & 3))
                     : (((kv - 16) >> 2) * 8 + 4 + ((kv - 16) & 3));
}

// ---------------------------------------------------------------------------
// fused preamble: job 0 = x fp32->bf16; job 1 = transpose+cvt w_qkv;
// job 2 = transpose+cvt w_proj. One launch instead of three.
__device__ __forceinline__ void tconv_body(const float* __restrict__ src,
                                           __bf16* __restrict__ dst,
                                           int R, int C, int c0, int r0, int t) {
    __shared__ float tile[32][33];
    const int tx = t & 31, ty = t >> 5;  // 32 x 8
    #pragma unroll
    for (int i = 0; i < 32; i += 8)
        tile[ty + i][tx] = src[(size_t)(r0 + ty + i) * C + c0 + tx];
    __syncthreads();
    #pragma unroll
    for (int i = 0; i < 32; i += 8)
        dst[(size_t)(c0 + ty + i) * R + r0 + tx] = (__bf16)tile[tx][ty + i];
}

__global__ __launch_bounds__(256)
void prep(const float* __restrict__ x, const float* __restrict__ w_qkv,
          const float* __restrict__ w_proj, __bf16* __restrict__ x_bf,
          __bf16* __restrict__ wqkvT, __bf16* __restrict__ wprojT) {
    const int bid = blockIdx.x;
    const int t = threadIdx.x;
    if (bid < 1024) {
        // cvt_x: 1,048,576 float4 over 1024 blocks x 256 threads x 4 iters
        const float4* xv = (const float4*)x;
        bf16x4* ov = (bf16x4*)x_bf;
        int i = bid * 256 + t;
        #pragma unroll
        for (int it = 0; it < 4; ++it, i += 262144) {
            float4 v = xv[i];
            bf16x4 r;
            r[0] = (__bf16)v.x; r[1] = (__bf16)v.y;
            r[2] = (__bf16)v.z; r[3] = (__bf16)v.w;
            ov[i] = r;
        }
    } else if (bid < 1024 + 3072) {
        const int b = bid - 1024;             // w_qkv: 96 x 32 tiles
        tconv_body(w_qkv, wqkvT, 1024, 3072, (b % 96) * 32, (b / 96) * 32, t);
    } else {
        const int b = bid - 4096;             // w_proj: 32 x 32 tiles
        tconv_body(w_proj, wprojT, 1024, 1024, (b & 31) * 32, (b >> 5) * 32, t);
    }
}

// ---------------------------------------------------------------------------
// 128x128 bf16 GEMM, Bt is [N][K]. C = A @ Bt^T + bias.
// Depth-2 counted-vmcnt pipeline (3 LDS buffers) + chunk-XOR LDS swizzle.
// 2D XCD chunking: XCD c covers an (gy/4) x (gx/2) tile rectangle traversed
// N-fastest, so the L2 strip (1 A-panel + gx/2 B-panels) stays resident.
// MODE 0: scatter Q (pre-scaled), K into [bh][n][d]; V -> sigma-interleaved
//         Vt [bh][d][n'].  MODE 1: plain fp32 [M][Nn] output.
template <int MODE>
__global__ __launch_bounds__(256)
void gemm128(const __bf16* __restrict__ A, const __bf16* __restrict__ Bt,
             const float* __restrict__ bias, void* __restrict__ outp,
             int M, int Nn, int K) {
    __shared__ __bf16 As[3][128][32];
    __shared__ __bf16 Bs[3][128][32];
    const int t = threadIdx.x;
    const int w = t >> 6, l = t & 63;
    const int lrow = l & 15, lhi = l >> 4;
    const int wr = (w >> 1) * 64, wc = (w & 1) * 64;

    // 2D XCD chunking (4 XCD-chunks along M x 2 along N)
    int m0, n0;
    {
        const int f = blockIdx.x + blockIdx.y * gridDim.x;
        if ((gridDim.y & 3) == 0 && (gridDim.x & 1) == 0) {
            const int c = f & 7, i = f >> 3;
            const int nch = gridDim.x >> 1;           // n-tiles per chunk
            const int mrow = i / nch, ncol = i % nch; // ncol fastest: B reuse
            m0 = ((c & 3) * (gridDim.y >> 2) + mrow) * 128;
            n0 = ((c >> 2) * nch + ncol) * 128;
        } else {
            m0 = blockIdx.y * 128; n0 = blockIdx.x * 128;
        }
    }

    f32x4 acc[4][4] = {};

    // staging: thread t -> row sr, linear dest chunk (t&3); source chunk
    // XOR-swizzled so physical chunk p holds semantic chunk p^((r>>1)&3)
    const int sr = t >> 2;
    const int dc = (t & 3) * 8;                          // dest elems (linear)
    const int scsw = ((t & 3) ^ ((sr >> 1) & 3)) * 8;    // swizzled src elems
    const __bf16* agb = A + (size_t)(m0 + sr) * K + scsw;
    const __bf16* bgb = Bt + (size_t)(n0 + sr) * K + scsw;

#define STAGE_G(BUF, KT)                                                   \
    { load_lds16(agb + (KT), &As[BUF][sr][dc]);                            \
      load_lds16(agb + (size_t)64 * K + (KT), &As[BUF][64 + sr][dc]);      \
      load_lds16(bgb + (KT), &Bs[BUF][sr][dc]);                            \
      load_lds16(bgb + (size_t)64 * K + (KT), &Bs[BUF][64 + sr][dc]); }

    STAGE_G(0, 0)
    STAGE_G(1, 32)

    const int rofs = (lhi ^ ((lrow >> 1) & 3)) << 4;     // read-side swizzle (bytes)
    const int nt = K >> 5;
    int cur = 0, pre = 2;
    for (int tt = 0; tt < nt; ++tt) {
        if (tt + 2 < nt) {
            STAGE_G(pre, (tt + 2) * 32)
            asm volatile("s_waitcnt vmcnt(8)" ::: "memory");
        } else if (tt + 1 < nt) {
            asm volatile("s_waitcnt vmcnt(4)" ::: "memory");
        } else {
            asm volatile("s_waitcnt vmcnt(0)" ::: "memory");
        }
        __builtin_amdgcn_sched_barrier(0);
        __builtin_amdgcn_s_barrier();        // all waves: tile tt fully in LDS
        __builtin_amdgcn_sched_barrier(0);

        bf16x8 af[4], bfv[4];
        #pragma unroll
        for (int i = 0; i < 4; ++i)
            af[i] = *(const bf16x8*)((const char*)&As[cur][wr + i * 16 + lrow][0] + rofs);
        #pragma unroll
        for (int j = 0; j < 4; ++j)
            bfv[j] = *(const bf16x8*)((const char*)&Bs[cur][wc + j * 16 + lrow][0] + rofs);
        __builtin_amdgcn_s_setprio(1);
        #pragma unroll
        for (int i = 0; i < 4; ++i)
            #pragma unroll
            for (int j = 0; j < 4; ++j)
                acc[i][j] = __builtin_amdgcn_mfma_f32_16x16x32_bf16(
                    af[i], bfv[j], acc[i][j], 0, 0, 0);
        __builtin_amdgcn_s_setprio(0);

        __builtin_amdgcn_sched_barrier(0);
        asm volatile("s_waitcnt lgkmcnt(0)" ::: "memory");  // reads of buf[cur] done
        __builtin_amdgcn_s_barrier();        // WAR: before buf[cur] is re-staged
        __builtin_amdgcn_sched_barrier(0);

        cur = (cur == 2) ? 0 : cur + 1;
        pre = (pre == 2) ? 0 : pre + 1;
    }
#undef STAGE_G

    #pragma unroll
    for (int i = 0; i < 4; ++i)
        #pragma unroll
        for (int j = 0; j < 4; ++j)
            #pragma unroll
            for (int r = 0; r < 4; ++r) {
                int row = m0 + wr + i * 16 + lhi * 4 + r;
                int col = n0 + wc + j * 16 + lrow;
                float val = acc[i][j][r] + bias[col];
                if (MODE == 0) {
                    int which = col >> 10;          // 0=q 1=k 2=v
                    int h = (col >> 6) & 15;
                    int d = col & 63;
                    int b = row >> 11;
                    int n = row & 2047;
                    int bh = (b << 4) + h;
                    if (which == 2) {
                        ((__bf16*)outp)[(size_t)2 * (32 * 2048 * 64) +
                                        ((size_t)bh * 64 + d) * 2048 +
                                        (n & ~31) + sigma32(n & 31)] = (__bf16)val;
                    } else {
                        if (which == 0) val *= QSCALE;
                        ((__bf16*)outp)[(size_t)which * (32 * 2048 * 64) +
                                        ((size_t)bh * 2048 + n) * 64 + d] = (__bf16)val;
                    }
                } else {
                    ((float*)outp)[(size_t)row * Nn + col] = val;
                }
            }
}

// ---------------------------------------------------------------------------
// flash attention, swapped-QK^T, in-register P, swizzled K/V LDS.
// KVBLK=128: one barrier + one staging burst per 128 kv; the inner body is
// the proven 64-kv step executed twice (half h = 0,1) on [dbuf][half] LDS.
// Each wave owns 32 q-rows (2 groups of 16 sharing K/V fragments).
// q,k: [32][2048][64] (q pre-scaled)   vt: [32][64][2048] sigma-interleaved
// out: [4096][1024] bf16
__global__ __launch_bounds__(256)
void attn_fwd(const __bf16* __restrict__ q, const __bf16* __restrict__ k,
              const __bf16* __restrict__ vt, __bf16* __restrict__ out) {
    __shared__ __bf16 KsV[2][2][64][64];   // [dbuf][half][kv][d]
    __shared__ __bf16 VsV[2][2][64][64];   // [dbuf][half][d][kv]
    char* ksB = (char*)KsV;
    char* vsB = (char*)VsV;

    const int t = threadIdx.x;
    const int w = t >> 6, l = t & 63;
    const int lrow = l & 15, lhi = l >> 4;
    const int bh = blockIdx.y;
    const int q0 = blockIdx.x * 128 + w * 32;

    const __bf16* qp = q + ((size_t)bh * 2048 + q0) * 64;
    bf16x8 qfA0 = *(const bf16x8*)(qp + lrow * 64 + lhi * 8);
    bf16x8 qfA1 = *(const bf16x8*)(qp + lrow * 64 + 32 + lhi * 8);
    bf16x8 qfB0 = *(const bf16x8*)(qp + (16 + lrow) * 64 + lhi * 8);
    bf16x8 qfB1 = *(const bf16x8*)(qp + (16 + lrow) * 64 + 32 + lhi * 8);

    f32x4 oA[4] = {}, oB[4] = {};
    float mA = -1e30f, mB = -1e30f;
    float lA = 0.f, lB = 0.f;

    const __bf16* kg = k + (size_t)bh * 2048 * 64;
    const __bf16* vg = vt + (size_t)bh * 64 * 2048;

    const int sr = t >> 3;
    const int sw8 = ((t & 7) ^ (sr & 7)) * 8;
    const int rsw = (lrow & 7) << 4;

    // prologue: stage kv 0..127 into dbuf 0 (both halves)
    {
        char* kd = ksB + t * 16;
        char* vd = vsB + t * 16;
        load_lds16(kg + (size_t)sr * 64 + sw8, kd);
        load_lds16(kg + (size_t)(32 + sr) * 64 + sw8, kd + 4096);
        load_lds16(kg + (size_t)(64 + sr) * 64 + sw8, kd + 8192);
        load_lds16(kg + (size_t)(96 + sr) * 64 + sw8, kd + 12288);
        load_lds16(vg + (size_t)sr * 2048 + sw8, vd);
        load_lds16(vg + (size_t)(32 + sr) * 2048 + sw8, vd + 4096);
        load_lds16(vg + (size_t)sr * 2048 + 64 + sw8, vd + 8192);
        load_lds16(vg + (size_t)(32 + sr) * 2048 + 64 + sw8, vd + 12288);
    }

    // strength-reduced prefetch pointers (next 128-kv tile)
    const __bf16* kst = kg + (size_t)(128 + sr) * 64 + sw8;   // += 8192/tile
    const __bf16* vst = vg + (size_t)sr * 2048 + 128 + sw8;   // += 128/tile

    int cur = 0;
    for (int kv0 = 0; kv0 < 2048; kv0 += 128) {
        __syncthreads();   // drains vmcnt -> dbuf[cur] ready for all waves
        if (kv0 + 128 < 2048) {
            char* kd = ksB + (cur ^ 1) * 16384 + t * 16;
            char* vd = vsB + (cur ^ 1) * 16384 + t * 16;
            load_lds16(kst, kd);
            load_lds16(kst + 32 * 64, kd + 4096);
            load_lds16(kst + 64 * 64, kd + 8192);
            load_lds16(kst + 96 * 64, kd + 12288);
            load_lds16(vst, vd);
            load_lds16(vst + 32 * 2048, vd + 4096);
            load_lds16(vst + 64, vd + 8192);
            load_lds16(vst + 32 * 2048 + 64, vd + 12288);
            kst += 8192; vst += 128;
        }
        #pragma unroll
        for (int h = 0; h < 2; ++h) {
            const char* kb = ksB + cur * 16384 + h * 8192 + lrow * 128;
            const char* vb = vsB + cur * 16384 + h * 8192 + lrow * 128;
            const int o0 = (lhi << 4) ^ rsw;
            const int o4 = ((4 + lhi) << 4) ^ rsw;

            f32x4 sA0 = {}, sA1 = {}, sA2 = {}, sA3 = {};
            f32x4 sB0 = {}, sB1 = {}, sB2 = {}, sB3 = {};
            __builtin_amdgcn_s_setprio(1);
            {
                bf16x8 kf0, kf1;
#define QK_GROUP(SA, SB, BASE)                                                 \
                kf0 = *(const bf16x8*)(kb + (BASE) + o0);                      \
                kf1 = *(const bf16x8*)(kb + (BASE) + o4);                      \
                SA = __builtin_amdgcn_mfma_f32_16x16x32_bf16(kf0, qfA0, SA, 0, 0, 0); \
                SA = __builtin_amdgcn_mfma_f32_16x16x32_bf16(kf1, qfA1, SA, 0, 0, 0); \
                SB = __builtin_amdgcn_mfma_f32_16x16x32_bf16(kf0, qfB0, SB, 0, 0, 0); \
                SB = __builtin_amdgcn_mfma_f32_16x16x32_bf16(kf1, qfB1, SB, 0, 0, 0);
                QK_GROUP(sA0, sB0, 0)
                QK_GROUP(sA1, sB1, 2048)
                QK_GROUP(sA2, sB2, 4096)
                QK_GROUP(sA3, sB3, 6144)
#undef QK_GROUP
            }
            __builtin_amdgcn_s_setprio(0);

            float u0 = m3(sA0[0], sA0[1], sA0[2]);
            float u1 = m3(sA0[3], sA1[0], sA1[1]);
            float u2 = m3(sA1[2], sA1[3], sA2[0]);
            float u3 = m3(sA2[1], sA2[2], sA2[3]);
            float u4 = m3(sA3[0], sA3[1], sA3[2]);
            float tmA = fmaxf(m3(u0, u1, u2), m3(u3, u4, sA3[3]));
            float v0 = m3(sB0[0], sB0[1], sB0[2]);
            float v1 = m3(sB0[3], sB1[0], sB1[1]);
            float v2 = m3(sB1[2], sB1[3], sB2[0]);
            float v3 = m3(sB2[1], sB2[2], sB2[3]);
            float v4 = m3(sB3[0], sB3[1], sB3[2]);
            float tmB = fmaxf(m3(v0, v1, v2), m3(v3, v4, sB3[3]));
            tmA = fmaxf(tmA, __shfl_xor(tmA, 16, 64));
            tmA = fmaxf(tmA, __shfl_xor(tmA, 32, 64));
            tmB = fmaxf(tmB, __shfl_xor(tmB, 16, 64));
            tmB = fmaxf(tmB, __shfl_xor(tmB, 32, 64));
            if (!__all(tmA <= mA + 8.0f && tmB <= mB + 8.0f)) {
                float mnA = fmaxf(mA, tmA), mnB = fmaxf(mB, tmB);
                float cA = __builtin_amdgcn_exp2f(mA - mnA);
                float cB = __builtin_amdgcn_exp2f(mB - mnB);
                lA *= cA; lB *= cB;
                #pragma unroll
                for (int dt = 0; dt < 4; ++dt)
                    #pragma unroll
                    for (int r = 0; r < 4; ++r) { oA[dt][r] *= cA; oB[dt][r] *= cB; }
                mA = mnA; mB = mnB;
            }
            float pA[16], pB[16];
            #pragma unroll
            for (int r = 0; r < 4; ++r) {
                pA[r]      = __builtin_amdgcn_exp2f(sA0[r] - mA);
                pA[4 + r]  = __builtin_amdgcn_exp2f(sA1[r] - mA);
                pA[8 + r]  = __builtin_amdgcn_exp2f(sA2[r] - mA);
                pA[12 + r] = __builtin_amdgcn_exp2f(sA3[r] - mA);
                pB[r]      = __builtin_amdgcn_exp2f(sB0[r] - mB);
                pB[4 + r]  = __builtin_amdgcn_exp2f(sB1[r] - mB);
                pB[8 + r]  = __builtin_amdgcn_exp2f(sB2[r] - mB);
                pB[12 + r] = __builtin_amdgcn_exp2f(sB3[r] - mB);
            }
            float rsA = 0.f, rsB = 0.f;
            #pragma unroll
            for (int j = 0; j < 16; ++j) { rsA += pA[j]; rsB += pB[j]; }
            lA += rsA; lB += rsB;

            bf16x8 pfA0, pfA1, pfB0, pfB1;
            #pragma unroll
            for (int j = 0; j < 8; ++j) {
                pfA0[j] = (__bf16)pA[j]; pfA1[j] = (__bf16)pA[8 + j];
                pfB0[j] = (__bf16)pB[j]; pfB1[j] = (__bf16)pB[8 + j];
            }

            __builtin_amdgcn_s_setprio(1);
            #pragma unroll
            for (int dt = 0; dt < 4; ++dt) {
                bf16x8 vf0 = *(const bf16x8*)(vb + dt * 2048 + o0);
                bf16x8 vf1 = *(const bf16x8*)(vb + dt * 2048 + o4);
                oA[dt] = __builtin_amdgcn_mfma_f32_16x16x32_bf16(vf0, pfA0, oA[dt], 0, 0, 0);
                oA[dt] = __builtin_amdgcn_mfma_f32_16x16x32_bf16(vf1, pfA1, oA[dt], 0, 0, 0);
                oB[dt] = __builtin_amdgcn_mfma_f32_16x16x32_bf16(vf0, pfB0, oB[dt], 0, 0, 0);
                oB[dt] = __builtin_amdgcn_mfma_f32_16x16x32_bf16(vf1, pfB1, oB[dt], 0, 0, 0);
            }
            __builtin_amdgcn_s_setprio(0);
        }
        cur ^= 1;
    }

    lA += __shfl_xor(lA, 16, 64); lA += __shfl_xor(lA, 32, 64);
    lB += __shfl_xor(lB, 16, 64); lB += __shfl_xor(lB, 32, 64);
    float invA = __builtin_amdgcn_rcpf(lA);
    float invB = __builtin_amdgcn_rcpf(lB);

    const int b = bh >> 4, h = bh & 15;
    __bf16* orowA = out + ((size_t)(b * 2048 + q0 + lrow)) * 1024 + h * 64;
    __bf16* orowB = out + ((size_t)(b * 2048 + q0 + 16 + lrow)) * 1024 + h * 64;
    #pragma unroll
    for (int dt = 0; dt < 4; ++dt) {
        bf16x4 ovA, ovB;
        #pragma unroll
        for (int r = 0; r < 4; ++r) {
            ovA[r] = (__bf16)(oA[dt][r] * invA);
            ovB[r] = (__bf16)(oB[dt][r] * invB);
        }
        *(bf16x4*)(orowA + dt * 16 + lhi * 4) = ovA;
        *(bf16x4*)(orowB + dt * 16 + lhi * 4) = ovB;
    }
}

// ---------------------------------------------------------------------------
extern "C" void kernel_launch(void* const* d_in, const int* in_sizes, int n_in,
                              void* d_out, int out_size, void* d_ws, size_t ws_size,
                              hipStream_t stream) {
    const float* x      = (const float*)d_in[0];
    const float* w_qkv  = (const float*)d_in[1];
    const float* b_qkv  = (const float*)d_in[2];
    const float* w_proj = (const float*)d_in[3];
    const float* b_proj = (const float*)d_in[4];
    float* out = (float*)d_out;

    __bf16* ws     = (__bf16*)d_ws;
    __bf16* x_bf   = ws;                          // 4096*1024
    __bf16* wqkvT  = x_bf + 4096 * 1024;          // 3072*1024
    __bf16* wprojT = wqkvT + 3072 * 1024;         // 1024*1024
    __bf16* qb     = wprojT + 1024 * 1024;        // 32*2048*64
    __bf16* kb     = qb + 32 * 2048 * 64;
    __bf16* vtb    = kb + 32 * 2048 * 64;         // sigma-interleaved V^T
    __bf16* attn   = vtb + 32 * 2048 * 64;        // 4096*1024

    prep<<<5120, 256, 0, stream>>>(x, w_qkv, w_proj, x_bf, wqkvT, wprojT);
    gemm128<0><<<dim3(24, 32), 256, 0, stream>>>(x_bf, wqkvT, b_qkv, qb, 4096, 3072, 1024);
    attn_fwd<<<dim3(16, 32), 256, 0, stream>>>(qb, kb, vtb, attn);
    gemm128<1><<<dim3(8, 32), 256, 0, stream>>>(attn, wprojT, b_proj, out, 4096, 1024, 1024);
}